// Round 6
// baseline (515.003 us; speedup 1.0000x reference)
//
#include <hip/hip_runtime.h>
#include <math.h>

#define D 128

typedef _Float16 half8 __attribute__((ext_vector_type(8)));
typedef _Float16 half4v __attribute__((ext_vector_type(4)));
typedef _Float16 half2v __attribute__((ext_vector_type(2)));
typedef float f32x4 __attribute__((ext_vector_type(4)));

// ================= CSR build (counting sort by dst) =================

__global__ void k_count(const int* __restrict__ ei, int* __restrict__ counts, int E) {
    int e0 = (blockIdx.x * blockDim.x + threadIdx.x) * 4;
    if (e0 + 3 < E) {
        int4 d4 = *(const int4*)(ei + E + e0);
        atomicAdd(&counts[d4.x], 1);
        atomicAdd(&counts[d4.y], 1);
        atomicAdd(&counts[d4.z], 1);
        atomicAdd(&counts[d4.w], 1);
    } else {
        for (int e = e0; e < E; e++) atomicAdd(&counts[ei[E + e]], 1);
    }
}

// scan over counts -> rowptr (exclusive); also emits dinv = rsqrt(count+1)
__global__ __launch_bounds__(256) void k_scan1(const int* __restrict__ counts,
                                               int* __restrict__ rowptr,
                                               int* __restrict__ bsums,
                                               float* __restrict__ dinv, int N) {
    __shared__ int sh[256];
    const int t = threadIdx.x;
    const int base = blockIdx.x * 1024 + t * 4;
    int c[4];
#pragma unroll
    for (int j = 0; j < 4; j++) c[j] = (base + j < N) ? counts[base + j] : 0;
#pragma unroll
    for (int j = 0; j < 4; j++)
        if (base + j < N) dinv[base + j] = rsqrtf((float)(c[j] + 1));
    int tsum = c[0] + c[1] + c[2] + c[3];
    sh[t] = tsum;
    __syncthreads();
    for (int off = 1; off < 256; off <<= 1) {
        int v = (t >= off) ? sh[t - off] : 0;
        __syncthreads();
        sh[t] += v;
        __syncthreads();
    }
    int run = (t == 0) ? 0 : sh[t - 1];
    if (t == 255) bsums[blockIdx.x] = sh[255];
#pragma unroll
    for (int j = 0; j < 4; j++) {
        if (base + j <= N) rowptr[base + j] = run;
        run += c[j];
    }
}

__global__ __launch_bounds__(128) void k_scan2(int* __restrict__ bsums, int NB) {
    __shared__ int sh[128];
    const int t = threadIdx.x;
    sh[t] = (t < NB) ? bsums[t] : 0;
    __syncthreads();
    for (int off = 1; off < 128; off <<= 1) {
        int v = (t >= off) ? sh[t - off] : 0;
        __syncthreads();
        sh[t] += v;
        __syncthreads();
    }
    if (t < NB) bsums[t] = (t == 0) ? 0 : sh[t - 1];
}

__global__ void k_scan3(int* __restrict__ rowptr, const int* __restrict__ bsums, int N) {
    int i = blockIdx.x * blockDim.x + threadIdx.x;
    if (i <= N) rowptr[i] += bsums[i >> 10];
}

__global__ void k_fill(const int* __restrict__ ei, int* __restrict__ cursor,
                       int* __restrict__ srcs, int E) {
    int e0 = (blockIdx.x * blockDim.x + threadIdx.x) * 4;
    if (e0 + 3 < E) {
        int4 s4 = *(const int4*)(ei + e0);
        int4 d4 = *(const int4*)(ei + E + e0);
        int p0 = atomicAdd(&cursor[d4.x], 1);
        int p1 = atomicAdd(&cursor[d4.y], 1);
        int p2 = atomicAdd(&cursor[d4.z], 1);
        int p3 = atomicAdd(&cursor[d4.w], 1);
        srcs[p0] = s4.x;
        srcs[p1] = s4.y;
        srcs[p2] = s4.z;
        srcs[p3] = s4.w;
    } else {
        for (int e = e0; e < E; e++) {
            int pos = atomicAdd(&cursor[ei[E + e]], 1);
            srcs[pos] = ei[e];
        }
    }
}

// ================= x -> fp16 =================

__global__ void k_cvt(const float* __restrict__ x, _Float16* __restrict__ y, int n8) {
    int i = blockIdx.x * blockDim.x + threadIdx.x;
    if (i >= n8) return;
    const float4 v0 = *(const float4*)(x + (size_t)i * 8);
    const float4 v1 = *(const float4*)(x + (size_t)i * 8 + 4);
    half8 h;
    h[0] = (_Float16)v0.x; h[1] = (_Float16)v0.y; h[2] = (_Float16)v0.z; h[3] = (_Float16)v0.w;
    h[4] = (_Float16)v1.x; h[5] = (_Float16)v1.y; h[6] = (_Float16)v1.z; h[7] = (_Float16)v1.w;
    *(half8*)(y + (size_t)i * 8) = h;
}

// ======== pre-pack conv weights into MFMA fragment layout (hi/lo split) ========
// slot = (s*8+c)*64 + lane; element j: k = s*32 + (lane>>4)*8 + j, n = c*16 + (lane&15)

__global__ __launch_bounds__(256) void k_prepw(const float* __restrict__ convW,
                                               _Float16* __restrict__ Whi,
                                               _Float16* __restrict__ Wlo) {
    const int l = blockIdx.x >> 3;                      // layer
    const int slot = (blockIdx.x & 7) * 256 + threadIdx.x;
    const float* W = convW + (size_t)l * D * D;
    const int p = slot >> 6, ln = slot & 63;
    const int s = p >> 3, c = p & 7;
    const int kbase = s * 32 + ((ln >> 4) << 3);
    const int n = (c << 4) + (ln & 15);
    half8 hv, lv;
#pragma unroll
    for (int j = 0; j < 8; j++) {
        float wv = W[(size_t)(kbase + j) * D + n];
        _Float16 h = (_Float16)wv;
        hv[j] = h;
        lv[j] = (_Float16)(wv - (float)h);
    }
    size_t base = (size_t)l * 2048 * 8 + (size_t)slot * 8;
    *(half8*)(Whi + base) = hv;
    *(half8*)(Wlo + base) = lv;
}

// ====== GEMM: hws = fp16((H16 @ W) * dinv[row]) — swapped-operand MFMA ======
// A_op = W fragment (from pre-packed global), B_op = H fragment.
// D[row=q*4+r -> W-col][col=lane&15 -> H-row]: per lane 4 CONSECUTIVE W-cols of one
// H-row -> 8-byte half4 stores. No LDS, no syncthreads.

__global__ __launch_bounds__(256) void k_gemm_mfma(
        const _Float16* __restrict__ H16,
        const _Float16* __restrict__ Whi, const _Float16* __restrict__ Wlo,
        const float* __restrict__ dinv, _Float16* __restrict__ hws, int N) {
    const int tid  = threadIdx.x;
    const int w    = tid >> 6;
    const int lane = tid & 63;
    const int q    = lane >> 4;
    const int l16  = lane & 15;
    const int rb0  = blockIdx.x * 128 + w * 32;

    f32x4 acc[2][8];
#pragma unroll
    for (int t = 0; t < 2; t++)
#pragma unroll
        for (int c = 0; c < 8; c++) acc[t][c] = (f32x4){0.f, 0.f, 0.f, 0.f};

#pragma unroll
    for (int s = 0; s < 4; s++) {
        half8 a[2];
#pragma unroll
        for (int t = 0; t < 2; t++) {
            int row = rb0 + t * 16 + l16;
            int rowc = row < N ? row : N - 1;
            a[t] = *(const half8*)(H16 + (size_t)rowc * D + s * 32 + q * 8);  // 16 B
        }
#pragma unroll
        for (int c = 0; c < 8; c++) {
            const size_t pb = (size_t)((s * 8 + c) * 64 + lane) * 8;
            half8 bh = *(const half8*)(Whi + pb);
            half8 bl = *(const half8*)(Wlo + pb);
#pragma unroll
            for (int t = 0; t < 2; t++) {
                acc[t][c] = __builtin_amdgcn_mfma_f32_16x16x32_f16(bl, a[t], acc[t][c], 0, 0, 0);
                acc[t][c] = __builtin_amdgcn_mfma_f32_16x16x32_f16(bh, a[t], acc[t][c], 0, 0, 0);
            }
        }
    }

    // epilogue: lane holds rows (rb0+t*16+l16), W-cols c*16+q*4+(0..3)
#pragma unroll
    for (int t = 0; t < 2; t++) {
        int row = rb0 + t * 16 + l16;
        if (row >= N) continue;
        float dv = dinv[row];
        _Float16* rp = hws + (size_t)row * D + q * 4;
#pragma unroll
        for (int c = 0; c < 8; c++) {
            half4v o;
            o[0] = (_Float16)(acc[t][c][0] * dv);
            o[1] = (_Float16)(acc[t][c][1] * dv);
            o[2] = (_Float16)(acc[t][c][2] * dv);
            o[3] = (_Float16)(acc[t][c][3] * dv);
            *(half4v*)(rp + c * 16) = o;   // 8 B store
        }
    }
}

// ====== aggregation: one wave per node, fp16 gathers, fp32 accumulate, fp16 out ======

__global__ __launch_bounds__(256) void k_agg(
        const int* __restrict__ rowptr, const int* __restrict__ srcs,
        const _Float16* __restrict__ hws, const float* __restrict__ dinv,
        const float* __restrict__ bias, _Float16* __restrict__ hout, int N) {
    int wid = (blockIdx.x * blockDim.x + threadIdx.x) >> 6;   // node index
    if (wid >= N) return;
    int lane = threadIdx.x & 63;
    int c = lane * 2;

    int beg = rowptr[wid];
    int end = rowptr[wid + 1];

    half2v sv = *(const half2v*)(hws + (size_t)wid * D + c);   // self-loop term
    float ax0 = (float)sv[0], ay0 = (float)sv[1];
    float ax1 = 0.f, ay1 = 0.f, ax2 = 0.f, ay2 = 0.f, ax3 = 0.f, ay3 = 0.f;

    int e = beg;
    for (; e + 4 <= end; e += 4) {
        int s0 = srcs[e], s1 = srcs[e + 1], s2 = srcs[e + 2], s3 = srcs[e + 3];
        half2v v0 = *(const half2v*)(hws + (size_t)s0 * D + c);
        half2v v1 = *(const half2v*)(hws + (size_t)s1 * D + c);
        half2v v2 = *(const half2v*)(hws + (size_t)s2 * D + c);
        half2v v3 = *(const half2v*)(hws + (size_t)s3 * D + c);
        ax0 += (float)v0[0]; ay0 += (float)v0[1];
        ax1 += (float)v1[0]; ay1 += (float)v1[1];
        ax2 += (float)v2[0]; ay2 += (float)v2[1];
        ax3 += (float)v3[0]; ay3 += (float)v3[1];
    }
    for (; e < end; e++) {
        int s = srcs[e];
        half2v v = *(const half2v*)(hws + (size_t)s * D + c);
        ax0 += (float)v[0]; ay0 += (float)v[1];
    }
    ax0 += ax1 + ax2 + ax3;
    ay0 += ay1 + ay2 + ay3;

    float sc = dinv[wid];
    float2 b = *(const float2*)(bias + c);
    half2v o;
    o[0] = (_Float16)fmaxf(fmaf(sc, ax0, b.x), 0.f);
    o[1] = (_Float16)fmaxf(fmaf(sc, ay0, b.y), 0.f);
    *(half2v*)(hout + (size_t)wid * D + c) = o;
}

// ========== fused pool + MLP head: one block (256 thr) per graph ==========

__global__ __launch_bounds__(256) void k_poolhead(
        const _Float16* __restrict__ h, const int* __restrict__ batch,
        const float* __restrict__ W1, const float* __restrict__ b1,
        const float* __restrict__ W2, const float* __restrict__ b2,
        const float* __restrict__ W3, const float* __restrict__ b3,
        float* __restrict__ out, int N) {
    __shared__ int sb[2];
    __shared__ float part[4][D];
    __shared__ float v[D];
    __shared__ float z[D];
    __shared__ float red[D];

    const int g = blockIdx.x;
    const int t = threadIdx.x;

    if (t < 2) {
        int target = g + t;
        int lo = 0, hi = N;
        while (lo < hi) {
            int mid = (lo + hi) >> 1;
            if (batch[mid] < target) lo = mid + 1; else hi = mid;
        }
        sb[t] = lo;
    }
    __syncthreads();
    const int rs = sb[0], re = sb[1];

    const int w = t >> 6;
    const int lane = t & 63;
    const int c = lane * 2;

    float ax = 0.f, ay = 0.f;
    for (int r = rs + w; r < re; r += 4) {
        half2v vv = *(const half2v*)(h + (size_t)r * D + c);
        ax += (float)vv[0]; ay += (float)vv[1];
    }
    part[w][c] = ax;
    part[w][c + 1] = ay;
    __syncthreads();

    if (t < D) v[t] = part[0][t] + part[1][t] + part[2][t] + part[3][t];
    __syncthreads();

    if (t < D) {
        float s = b1[t];
        for (int k = 0; k < D; k++) s = fmaf(v[k], W1[(size_t)k * D + t], s);
        z[t] = fmaxf(s, 0.f);
    }
    __syncthreads();

    if (t < D) {
        float s = b2[t];
        for (int k = 0; k < D; k++) s = fmaf(z[k], W2[(size_t)k * D + t], s);
        red[t] = fmaxf(s, 0.f) * W3[t];
    }
    __syncthreads();
    for (int off = 64; off >= 1; off >>= 1) {
        if (t < off) red[t] += red[t + off];
        __syncthreads();
    }
    if (t == 0) out[g] = 1.f / (1.f + expf(-(red[0] + b3[0])));
}

// ================= orchestration =================

extern "C" void kernel_launch(void* const* d_in, const int* in_sizes, int n_in,
                              void* d_out, int out_size, void* d_ws, size_t ws_size,
                              hipStream_t stream) {
    const float* x     = (const float*)d_in[0];
    const int*   ei    = (const int*)d_in[1];
    const int*   batch = (const int*)d_in[2];
    const float* convW = (const float*)d_in[3];
    const float* convB = (const float*)d_in[4];
    const float* W1 = (const float*)d_in[5];
    const float* b1 = (const float*)d_in[6];
    const float* W2 = (const float*)d_in[7];
    const float* b2 = (const float*)d_in[8];
    const float* W3 = (const float*)d_in[9];
    const float* b3 = (const float*)d_in[10];
    float* out = (float*)d_out;

    const int N = in_sizes[0] / D;          // 100000
    const int E = in_sizes[1] / 2;          // 640000
    const int G = out_size;                 // 512
    const int NB = (N + 1023) / 1024;

    // ---- workspace layout ----
    char* w = (char*)d_ws;
    size_t off = 0;
    auto alloc = [&](size_t bytes) -> char* {
        char* p = w + off;
        off += (bytes + 255) & ~(size_t)255;
        return p;
    };
    float*     dinv   = (float*)alloc((size_t)N * 4);
    _Float16*  x16    = (_Float16*)alloc((size_t)N * D * 2);
    _Float16*  hws    = (_Float16*)alloc((size_t)N * D * 2);
    _Float16*  hbuf   = (_Float16*)alloc((size_t)N * D * 2);
    _Float16*  Whi    = (_Float16*)alloc((size_t)4 * D * D * 2);
    _Float16*  Wlo    = (_Float16*)alloc((size_t)4 * D * D * 2);
    int*       counts = (int*)alloc((size_t)N * 4);
    int*       rowptr = (int*)alloc((size_t)(N + 1) * 4);
    int*       cursor = (int*)alloc((size_t)N * 4);
    int*       srcs   = (int*)alloc((size_t)E * 4);
    int*       bsums  = (int*)alloc((size_t)NB * 4);

    // ---- CSR build + input convert + weight pre-pack ----
    hipMemsetAsync(counts, 0, (size_t)N * 4, stream);
    k_count<<<(E / 4 + 255) / 256, 256, 0, stream>>>(ei, counts, E);
    k_prepw<<<32, 256, 0, stream>>>(convW, Whi, Wlo);
    k_cvt<<<(N * D / 8 + 255) / 256, 256, 0, stream>>>(x, x16, N * D / 8);
    k_scan1<<<NB, 256, 0, stream>>>(counts, rowptr, bsums, dinv, N);
    k_scan2<<<1, 128, 0, stream>>>(bsums, NB);
    k_scan3<<<(N + 1 + 255) / 256, 256, 0, stream>>>(rowptr, bsums, N);
    hipMemcpyAsync(cursor, rowptr, (size_t)N * 4, hipMemcpyDeviceToDevice, stream);
    k_fill<<<(E / 4 + 255) / 256, 256, 0, stream>>>(ei, cursor, srcs, E);

    // ---- 4 GCN layers ----
    const int gemm_grid = (N + 127) / 128;
    const int agg_grid  = (N + 3) / 4;

    const _Float16* hin = x16;
    for (int l = 0; l < 4; l++) {
        k_gemm_mfma<<<gemm_grid, 256, 0, stream>>>(hin, Whi + (size_t)l * D * D,
                                                   Wlo + (size_t)l * D * D,
                                                   dinv, hws, N);
        k_agg<<<agg_grid, 256, 0, stream>>>(rowptr, srcs, hws, dinv,
                                            convB + (size_t)l * D, hbuf, N);
        hin = hbuf;
    }

    // ---- fused pool + head ----
    k_poolhead<<<G, 256, 0, stream>>>(hin, batch, W1, b1, W2, b2, W3, b3, out, N);
}

// Round 7
// 479.933 us; speedup vs baseline: 1.0731x; 1.0731x over previous
//
#include <hip/hip_runtime.h>
#include <math.h>

#define D 128
#define LSTRIDE 136   // LDS row stride in halves: 68 dwords -> bank-start 4*(l16+q)%32, 2-way on writes

typedef _Float16 half8 __attribute__((ext_vector_type(8)));
typedef _Float16 half4v __attribute__((ext_vector_type(4)));
typedef _Float16 half2v __attribute__((ext_vector_type(2)));
typedef float f32x4 __attribute__((ext_vector_type(4)));

// ================= CSR build (counting sort by dst) =================

__global__ void k_count(const int* __restrict__ ei, int* __restrict__ counts, int E) {
    int e0 = (blockIdx.x * blockDim.x + threadIdx.x) * 4;
    if (e0 + 3 < E) {
        int4 d4 = *(const int4*)(ei + E + e0);
        atomicAdd(&counts[d4.x], 1);
        atomicAdd(&counts[d4.y], 1);
        atomicAdd(&counts[d4.z], 1);
        atomicAdd(&counts[d4.w], 1);
    } else {
        for (int e = e0; e < E; e++) atomicAdd(&counts[ei[E + e]], 1);
    }
}

// scan counts -> rowptr (exclusive); emits dinv = rsqrt(count+1)
__global__ __launch_bounds__(256) void k_scan1(const int* __restrict__ counts,
                                               int* __restrict__ rowptr,
                                               int* __restrict__ bsums,
                                               float* __restrict__ dinv, int N) {
    __shared__ int sh[256];
    const int t = threadIdx.x;
    const int base = blockIdx.x * 1024 + t * 4;
    int c[4];
#pragma unroll
    for (int j = 0; j < 4; j++) c[j] = (base + j < N) ? counts[base + j] : 0;
#pragma unroll
    for (int j = 0; j < 4; j++)
        if (base + j < N) dinv[base + j] = rsqrtf((float)(c[j] + 1));
    int tsum = c[0] + c[1] + c[2] + c[3];
    sh[t] = tsum;
    __syncthreads();
    for (int off = 1; off < 256; off <<= 1) {
        int v = (t >= off) ? sh[t - off] : 0;
        __syncthreads();
        sh[t] += v;
        __syncthreads();
    }
    int run = (t == 0) ? 0 : sh[t - 1];
    if (t == 255) bsums[blockIdx.x] = sh[255];
#pragma unroll
    for (int j = 0; j < 4; j++) {
        if (base + j <= N) rowptr[base + j] = run;
        run += c[j];
    }
}

__global__ __launch_bounds__(128) void k_scan2(int* __restrict__ bsums, int NB) {
    __shared__ int sh[128];
    const int t = threadIdx.x;
    sh[t] = (t < NB) ? bsums[t] : 0;
    __syncthreads();
    for (int off = 1; off < 128; off <<= 1) {
        int v = (t >= off) ? sh[t - off] : 0;
        __syncthreads();
        sh[t] += v;
        __syncthreads();
    }
    if (t < NB) bsums[t] = (t == 0) ? 0 : sh[t - 1];
}

// add block offsets; also initialize cursor = rowptr (kills the d2d memcpy)
__global__ void k_scan3(int* __restrict__ rowptr, int* __restrict__ cursor,
                        const int* __restrict__ bsums, int N) {
    int i = blockIdx.x * blockDim.x + threadIdx.x;
    if (i <= N) {
        int v = rowptr[i] + bsums[i >> 10];
        rowptr[i] = v;
        if (i < N) cursor[i] = v;
    }
}

__global__ void k_fill(const int* __restrict__ ei, int* __restrict__ cursor,
                       int* __restrict__ srcs, int E) {
    int e0 = (blockIdx.x * blockDim.x + threadIdx.x) * 4;
    if (e0 + 3 < E) {
        int4 s4 = *(const int4*)(ei + e0);
        int4 d4 = *(const int4*)(ei + E + e0);
        int p0 = atomicAdd(&cursor[d4.x], 1);
        int p1 = atomicAdd(&cursor[d4.y], 1);
        int p2 = atomicAdd(&cursor[d4.z], 1);
        int p3 = atomicAdd(&cursor[d4.w], 1);
        srcs[p0] = s4.x;
        srcs[p1] = s4.y;
        srcs[p2] = s4.z;
        srcs[p3] = s4.w;
    } else {
        for (int e = e0; e < E; e++) {
            int pos = atomicAdd(&cursor[ei[E + e]], 1);
            srcs[pos] = ei[e];
        }
    }
}

// ================= g0 = fp16(dinv[row] * x) =================

__global__ void k_cvt(const float* __restrict__ x, const float* __restrict__ dinv,
                      _Float16* __restrict__ y, int n8) {
    int i = blockIdx.x * blockDim.x + threadIdx.x;
    if (i >= n8) return;
    float s = dinv[i >> 4];                       // row = (i*8)/128
    const float4 v0 = *(const float4*)(x + (size_t)i * 8);
    const float4 v1 = *(const float4*)(x + (size_t)i * 8 + 4);
    half8 h;
    h[0] = (_Float16)(v0.x * s); h[1] = (_Float16)(v0.y * s);
    h[2] = (_Float16)(v0.z * s); h[3] = (_Float16)(v0.w * s);
    h[4] = (_Float16)(v1.x * s); h[5] = (_Float16)(v1.y * s);
    h[6] = (_Float16)(v1.z * s); h[7] = (_Float16)(v1.w * s);
    *(half8*)(y + (size_t)i * 8) = h;
}

// ======== pre-pack conv weights into MFMA fragment layout (hi/lo split) ========
// slot = (s*8+c)*64 + lane; element j: k = s*32 + (lane>>4)*8 + j, n = c*16 + (lane&15)

__global__ __launch_bounds__(256) void k_prepw(const float* __restrict__ convW,
                                               _Float16* __restrict__ Whi,
                                               _Float16* __restrict__ Wlo) {
    const int l = blockIdx.x >> 3;                      // layer
    const int slot = (blockIdx.x & 7) * 256 + threadIdx.x;
    const float* W = convW + (size_t)l * D * D;
    const int p = slot >> 6, ln = slot & 63;
    const int s = p >> 3, c = p & 7;
    const int kbase = s * 32 + ((ln >> 4) << 3);
    const int n = (c << 4) + (ln & 15);
    half8 hv, lv;
#pragma unroll
    for (int j = 0; j < 8; j++) {
        float wv = W[(size_t)(kbase + j) * D + n];
        _Float16 h = (_Float16)wv;
        hv[j] = h;
        lv[j] = (_Float16)(wv - (float)h);
    }
    size_t base = (size_t)l * 2048 * 8 + (size_t)slot * 8;
    *(half8*)(Whi + base) = hv;
    *(half8*)(Wlo + base) = lv;
}

// ============ fused layer: gout = scale ⊙ relu( (dinv ⊙ Â g) @ W + b ) ============
// Uses (Â h) W = Â (h W): aggregate prescaled g rows first (wave/node, fp32 acc),
// drop S = dinv[dst]*(Σ g[src] + g[dst]) into LDS fp16, then swapped-operand MFMA
// with pre-packed W fragments. scale = dinv (inner layers) or 1 (last, for pooling).
// Block: 512 thr = 8 waves; 128 nodes/block. LDS 128 x LSTRIDE halves.

__global__ __launch_bounds__(512) void k_layer(
        const _Float16* __restrict__ gin,
        const int* __restrict__ rowptr, const int* __restrict__ srcs,
        const float* __restrict__ dinv,
        const _Float16* __restrict__ Whi, const _Float16* __restrict__ Wlo,
        const float* __restrict__ bias,
        _Float16* __restrict__ gout, int N, int last) {
    __shared__ _Float16 S[128 * LSTRIDE];

    const int tid  = threadIdx.x;
    const int w    = tid >> 6;
    const int lane = tid & 63;
    const int q    = lane >> 4;
    const int l16  = lane & 15;
    const int nb0  = blockIdx.x * 128;

    // ---- phase 1: gather. wave w handles nodes w*16 .. w*16+15 (local) ----
    const int c = lane * 2;
    for (int it = 0; it < 16; ++it) {
        const int nl = w * 16 + it;
        const int node = nb0 + nl;
        float ax0 = 0.f, ay0 = 0.f, ax1 = 0.f, ay1 = 0.f;
        float ax2 = 0.f, ay2 = 0.f, ax3 = 0.f, ay3 = 0.f;
        if (node < N) {
            const int beg = rowptr[node];
            const int end = rowptr[node + 1];
            half2v sv = *(const half2v*)(gin + (size_t)node * D + c);  // self-loop
            ax0 = (float)sv[0]; ay0 = (float)sv[1];
            int e = beg;
            for (; e + 4 <= end; e += 4) {
                int s0 = srcs[e], s1 = srcs[e + 1], s2 = srcs[e + 2], s3 = srcs[e + 3];
                half2v v0 = *(const half2v*)(gin + (size_t)s0 * D + c);
                half2v v1 = *(const half2v*)(gin + (size_t)s1 * D + c);
                half2v v2 = *(const half2v*)(gin + (size_t)s2 * D + c);
                half2v v3 = *(const half2v*)(gin + (size_t)s3 * D + c);
                ax0 += (float)v0[0]; ay0 += (float)v0[1];
                ax1 += (float)v1[0]; ay1 += (float)v1[1];
                ax2 += (float)v2[0]; ay2 += (float)v2[1];
                ax3 += (float)v3[0]; ay3 += (float)v3[1];
            }
            for (; e < end; e++) {
                int s0 = srcs[e];
                half2v v = *(const half2v*)(gin + (size_t)s0 * D + c);
                ax0 += (float)v[0]; ay0 += (float)v[1];
            }
            float sc = dinv[node];
            ax0 = (ax0 + ax1 + ax2 + ax3) * sc;
            ay0 = (ay0 + ay1 + ay2 + ay3) * sc;
        }
        half2v o;
        o[0] = (_Float16)ax0;
        o[1] = (_Float16)ay0;
        *(half2v*)(&S[nl * LSTRIDE + c]) = o;
    }
    __syncthreads();

    // ---- phase 2: S @ W via MFMA (A_op = W frag, B_op = S frag) ----
    f32x4 acc[8];
#pragma unroll
    for (int cc = 0; cc < 8; cc++) acc[cc] = (f32x4){0.f, 0.f, 0.f, 0.f};

    const int nl = w * 16 + l16;          // this lane's node row (B-frag)
#pragma unroll
    for (int s = 0; s < 4; s++) {
        half8 bf = *(const half8*)(&S[nl * LSTRIDE + s * 32 + q * 8]);
#pragma unroll
        for (int cc = 0; cc < 8; cc++) {
            const size_t pb = (size_t)((s * 8 + cc) * 64 + lane) * 8;
            half8 wh = *(const half8*)(Whi + pb);
            half8 wl = *(const half8*)(Wlo + pb);
            acc[cc] = __builtin_amdgcn_mfma_f32_16x16x32_f16(wl, bf, acc[cc], 0, 0, 0);
            acc[cc] = __builtin_amdgcn_mfma_f32_16x16x32_f16(wh, bf, acc[cc], 0, 0, 0);
        }
    }

    // epilogue: D[m = W-col = q*4+r][n = node = l16]
    const int node = nb0 + nl;
    if (node < N) {
        const float scale = last ? 1.0f : dinv[node];
        _Float16* rp = gout + (size_t)node * D + q * 4;
#pragma unroll
        for (int cc = 0; cc < 8; cc++) {
            const float4 bc = *(const float4*)(bias + cc * 16 + q * 4);
            half4v o;
            o[0] = (_Float16)(fmaxf(acc[cc][0] + bc.x, 0.f) * scale);
            o[1] = (_Float16)(fmaxf(acc[cc][1] + bc.y, 0.f) * scale);
            o[2] = (_Float16)(fmaxf(acc[cc][2] + bc.z, 0.f) * scale);
            o[3] = (_Float16)(fmaxf(acc[cc][3] + bc.w, 0.f) * scale);
            *(half4v*)(rp + cc * 16) = o;   // 8 B store
        }
    }
}

// ========== fused pool + MLP head: one block (256 thr) per graph ==========

__global__ __launch_bounds__(256) void k_poolhead(
        const _Float16* __restrict__ h, const int* __restrict__ batch,
        const float* __restrict__ W1, const float* __restrict__ b1,
        const float* __restrict__ W2, const float* __restrict__ b2,
        const float* __restrict__ W3, const float* __restrict__ b3,
        float* __restrict__ out, int N) {
    __shared__ int sb[2];
    __shared__ float part[4][D];
    __shared__ float v[D];
    __shared__ float z[D];
    __shared__ float red[D];

    const int g = blockIdx.x;
    const int t = threadIdx.x;

    if (t < 2) {
        int target = g + t;
        int lo = 0, hi = N;
        while (lo < hi) {
            int mid = (lo + hi) >> 1;
            if (batch[mid] < target) lo = mid + 1; else hi = mid;
        }
        sb[t] = lo;
    }
    __syncthreads();
    const int rs = sb[0], re = sb[1];

    const int w = t >> 6;
    const int lane = t & 63;
    const int c = lane * 2;

    float ax = 0.f, ay = 0.f;
    for (int r = rs + w; r < re; r += 4) {
        half2v vv = *(const half2v*)(h + (size_t)r * D + c);
        ax += (float)vv[0]; ay += (float)vv[1];
    }
    part[w][c] = ax;
    part[w][c + 1] = ay;
    __syncthreads();

    if (t < D) v[t] = part[0][t] + part[1][t] + part[2][t] + part[3][t];
    __syncthreads();

    if (t < D) {
        float s = b1[t];
        for (int k = 0; k < D; k++) s = fmaf(v[k], W1[(size_t)k * D + t], s);
        z[t] = fmaxf(s, 0.f);
    }
    __syncthreads();

    if (t < D) {
        float s = b2[t];
        for (int k = 0; k < D; k++) s = fmaf(z[k], W2[(size_t)k * D + t], s);
        red[t] = fmaxf(s, 0.f) * W3[t];
    }
    __syncthreads();
    for (int off = 64; off >= 1; off >>= 1) {
        if (t < off) red[t] += red[t + off];
        __syncthreads();
    }
    if (t == 0) out[g] = 1.f / (1.f + expf(-(red[0] + b3[0])));
}

// ================= orchestration =================

extern "C" void kernel_launch(void* const* d_in, const int* in_sizes, int n_in,
                              void* d_out, int out_size, void* d_ws, size_t ws_size,
                              hipStream_t stream) {
    const float* x     = (const float*)d_in[0];
    const int*   ei    = (const int*)d_in[1];
    const int*   batch = (const int*)d_in[2];
    const float* convW = (const float*)d_in[3];
    const float* convB = (const float*)d_in[4];
    const float* W1 = (const float*)d_in[5];
    const float* b1 = (const float*)d_in[6];
    const float* W2 = (const float*)d_in[7];
    const float* b2 = (const float*)d_in[8];
    const float* W3 = (const float*)d_in[9];
    const float* b3 = (const float*)d_in[10];
    float* out = (float*)d_out;

    const int N = in_sizes[0] / D;          // 100000
    const int E = in_sizes[1] / 2;          // 640000
    const int G = out_size;                 // 512
    const int NB = (N + 1023) / 1024;

    // ---- workspace layout ----
    char* w = (char*)d_ws;
    size_t off = 0;
    auto alloc = [&](size_t bytes) -> char* {
        char* p = w + off;
        off += (bytes + 255) & ~(size_t)255;
        return p;
    };
    float*     dinv   = (float*)alloc((size_t)N * 4);
    _Float16*  gA     = (_Float16*)alloc((size_t)N * D * 2);
    _Float16*  gB     = (_Float16*)alloc((size_t)N * D * 2);
    _Float16*  Whi    = (_Float16*)alloc((size_t)4 * D * D * 2);
    _Float16*  Wlo    = (_Float16*)alloc((size_t)4 * D * D * 2);
    int*       counts = (int*)alloc((size_t)N * 4);
    int*       rowptr = (int*)alloc((size_t)(N + 1) * 4);
    int*       cursor = (int*)alloc((size_t)N * 4);
    int*       srcs   = (int*)alloc((size_t)E * 4);
    int*       bsums  = (int*)alloc((size_t)NB * 4);

    // ---- CSR build + weight pre-pack + input convert ----
    hipMemsetAsync(counts, 0, (size_t)N * 4, stream);
    k_count<<<(E / 4 + 255) / 256, 256, 0, stream>>>(ei, counts, E);
    k_prepw<<<32, 256, 0, stream>>>(convW, Whi, Wlo);
    k_scan1<<<NB, 256, 0, stream>>>(counts, rowptr, bsums, dinv, N);
    k_cvt<<<(N * D / 8 + 255) / 256, 256, 0, stream>>>(x, dinv, gA, N * D / 8);
    k_scan2<<<1, 128, 0, stream>>>(bsums, NB);
    k_scan3<<<(N + 1 + 255) / 256, 256, 0, stream>>>(rowptr, cursor, bsums, N);
    k_fill<<<(E / 4 + 255) / 256, 256, 0, stream>>>(ei, cursor, srcs, E);

    // ---- 4 fused GCN layers (ping-pong) ----
    const int layer_grid = (N + 127) / 128;
    const _Float16* gi = gA;
    _Float16* go = gB;
    for (int l = 0; l < 4; l++) {
        k_layer<<<layer_grid, 512, 0, stream>>>(gi, rowptr, srcs, dinv,
                                                Whi + (size_t)l * D * D,
                                                Wlo + (size_t)l * D * D,
                                                convB + (size_t)l * D,
                                                go, N, l == 3);
        const _Float16* tmp = go;
        go = (_Float16*)gi;
        gi = tmp;
    }

    // ---- fused pool + head (final features in gi after swap) ----
    k_poolhead<<<G, 256, 0, stream>>>(gi, batch, W1, b1, W2, b2, W3, b3, out, N);
}

// Round 8
// 423.131 us; speedup vs baseline: 1.2171x; 1.1342x over previous
//
#include <hip/hip_runtime.h>
#include <math.h>

#define D 128
#define LSTRIDE 136   // LDS row stride in halves

typedef _Float16 half8 __attribute__((ext_vector_type(8)));
typedef _Float16 half4v __attribute__((ext_vector_type(4)));
typedef _Float16 half2v __attribute__((ext_vector_type(2)));
typedef float f32x4 __attribute__((ext_vector_type(4)));

// ================= CSR build (counting sort by dst) =================

__global__ void k_count(const int* __restrict__ ei, int* __restrict__ counts, int E) {
    int e0 = (blockIdx.x * blockDim.x + threadIdx.x) * 4;
    if (e0 + 3 < E) {
        int4 d4 = *(const int4*)(ei + E + e0);
        atomicAdd(&counts[d4.x], 1);
        atomicAdd(&counts[d4.y], 1);
        atomicAdd(&counts[d4.z], 1);
        atomicAdd(&counts[d4.w], 1);
    } else {
        for (int e = e0; e < E; e++) atomicAdd(&counts[ei[E + e]], 1);
    }
}

// scan counts -> rowptr (exclusive); emits dinv = rsqrt(count+1)
__global__ __launch_bounds__(256) void k_scan1(const int* __restrict__ counts,
                                               int* __restrict__ rowptr,
                                               int* __restrict__ bsums,
                                               float* __restrict__ dinv, int N) {
    __shared__ int sh[256];
    const int t = threadIdx.x;
    const int base = blockIdx.x * 1024 + t * 4;
    int c[4];
#pragma unroll
    for (int j = 0; j < 4; j++) c[j] = (base + j < N) ? counts[base + j] : 0;
#pragma unroll
    for (int j = 0; j < 4; j++)
        if (base + j < N) dinv[base + j] = rsqrtf((float)(c[j] + 1));
    int tsum = c[0] + c[1] + c[2] + c[3];
    sh[t] = tsum;
    __syncthreads();
    for (int off = 1; off < 256; off <<= 1) {
        int v = (t >= off) ? sh[t - off] : 0;
        __syncthreads();
        sh[t] += v;
        __syncthreads();
    }
    int run = (t == 0) ? 0 : sh[t - 1];
    if (t == 255) bsums[blockIdx.x] = sh[255];
#pragma unroll
    for (int j = 0; j < 4; j++) {
        if (base + j <= N) rowptr[base + j] = run;
        run += c[j];
    }
}

__global__ __launch_bounds__(128) void k_scan2(int* __restrict__ bsums, int NB) {
    __shared__ int sh[128];
    const int t = threadIdx.x;
    sh[t] = (t < NB) ? bsums[t] : 0;
    __syncthreads();
    for (int off = 1; off < 128; off <<= 1) {
        int v = (t >= off) ? sh[t - off] : 0;
        __syncthreads();
        sh[t] += v;
        __syncthreads();
    }
    if (t < NB) bsums[t] = (t == 0) ? 0 : sh[t - 1];
}

// add block offsets; also initialize cursor = rowptr
__global__ void k_scan3(int* __restrict__ rowptr, int* __restrict__ cursor,
                        const int* __restrict__ bsums, int N) {
    int i = blockIdx.x * blockDim.x + threadIdx.x;
    if (i <= N) {
        int v = rowptr[i] + bsums[i >> 10];
        rowptr[i] = v;
        if (i < N) cursor[i] = v;
    }
}

__global__ void k_fill(const int* __restrict__ ei, int* __restrict__ cursor,
                       int* __restrict__ srcs, int E) {
    int e0 = (blockIdx.x * blockDim.x + threadIdx.x) * 4;
    if (e0 + 3 < E) {
        int4 s4 = *(const int4*)(ei + e0);
        int4 d4 = *(const int4*)(ei + E + e0);
        int p0 = atomicAdd(&cursor[d4.x], 1);
        int p1 = atomicAdd(&cursor[d4.y], 1);
        int p2 = atomicAdd(&cursor[d4.z], 1);
        int p3 = atomicAdd(&cursor[d4.w], 1);
        srcs[p0] = s4.x;
        srcs[p1] = s4.y;
        srcs[p2] = s4.z;
        srcs[p3] = s4.w;
    } else {
        for (int e = e0; e < E; e++) {
            int pos = atomicAdd(&cursor[ei[E + e]], 1);
            srcs[pos] = ei[e];
        }
    }
}

// ================= g0 = fp16(dinv[row] * x) =================

__global__ void k_cvt(const float* __restrict__ x, const float* __restrict__ dinv,
                      _Float16* __restrict__ y, int n8) {
    int i = blockIdx.x * blockDim.x + threadIdx.x;
    if (i >= n8) return;
    float s = dinv[i >> 4];
    const float4 v0 = *(const float4*)(x + (size_t)i * 8);
    const float4 v1 = *(const float4*)(x + (size_t)i * 8 + 4);
    half8 h;
    h[0] = (_Float16)(v0.x * s); h[1] = (_Float16)(v0.y * s);
    h[2] = (_Float16)(v0.z * s); h[3] = (_Float16)(v0.w * s);
    h[4] = (_Float16)(v1.x * s); h[5] = (_Float16)(v1.y * s);
    h[6] = (_Float16)(v1.z * s); h[7] = (_Float16)(v1.w * s);
    *(half8*)(y + (size_t)i * 8) = h;
}

// ======== pre-pack conv weights into MFMA fragment layout (single fp16) ========
// slot = (s*8+c)*64 + lane; element j: k = s*32 + (lane>>4)*8 + j, n = c*16 + (lane&15)

__global__ __launch_bounds__(256) void k_prepw(const float* __restrict__ convW,
                                               _Float16* __restrict__ Wf) {
    const int l = blockIdx.x >> 3;                      // layer
    const int slot = (blockIdx.x & 7) * 256 + threadIdx.x;
    const float* W = convW + (size_t)l * D * D;
    const int p = slot >> 6, ln = slot & 63;
    const int s = p >> 3, c = p & 7;
    const int kbase = s * 32 + ((ln >> 4) << 3);
    const int n = (c << 4) + (ln & 15);
    half8 hv;
#pragma unroll
    for (int j = 0; j < 8; j++) hv[j] = (_Float16)W[(size_t)(kbase + j) * D + n];
    *(half8*)(Wf + (size_t)l * D * D + (size_t)slot * 8) = hv;
}

// ============ fused layer: gout = scale ⊙ relu( (dinv ⊙ Â g) @ W + b ) ============
// Phase 1: gather — each 16-lane group owns one node, loads whole 256 B rows as
// half8 (dwordx4); 4 nodes per wave in flight, no cross-lane reduce.
// Phase 2: S @ W via swapped-operand MFMA, W fragments staged in LDS.
// Block: 512 thr = 8 waves; 128 nodes/block.

__global__ __launch_bounds__(512) void k_layer(
        const _Float16* __restrict__ gin,
        const int* __restrict__ rowptr, const int* __restrict__ srcs,
        const float* __restrict__ dinv,
        const _Float16* __restrict__ Wf,
        const float* __restrict__ bias,
        _Float16* __restrict__ gout, int N, int last) {
    __shared__ _Float16 S[128 * LSTRIDE];   // 34.8 KB
    __shared__ _Float16 WL[2048 * 8];       // 32 KB

    const int tid  = threadIdx.x;
    const int w    = tid >> 6;
    const int lane = tid & 63;
    const int q    = lane >> 4;       // group 0..3
    const int l16  = lane & 15;       // lane-in-group; col base = l16*8
    const int nb0  = blockIdx.x * 128;

    // stage W fragments into LDS (coalesced; covered by the phase-1 barrier)
    {
        const half8* wsrc = (const half8*)Wf;
        half8* wdst = (half8*)WL;
        for (int i = tid; i < 2048; i += 512) wdst[i] = wsrc[i];
    }

    // ---- phase 1: gather; wave w covers nodes w*16..w*16+15, group q owns q*4+it ----
    const int cb = l16 * 8;
    for (int it = 0; it < 4; ++it) {
        const int nl = w * 16 + q * 4 + it;
        const int node = nb0 + nl;
        float a[8];
#pragma unroll
        for (int j = 0; j < 8; j++) a[j] = 0.f;

        if (node < N) {
            half8 sv = *(const half8*)(gin + (size_t)node * D + cb);  // self-loop
#pragma unroll
            for (int j = 0; j < 8; j++) a[j] = (float)sv[j];
            const int beg = rowptr[node];
            const int end = rowptr[node + 1];
            int e = beg;
            for (; e + 1 < end; e += 2) {
                int s0 = srcs[e];
                int s1 = srcs[e + 1];
                half8 v0 = *(const half8*)(gin + (size_t)s0 * D + cb);
                half8 v1 = *(const half8*)(gin + (size_t)s1 * D + cb);
#pragma unroll
                for (int j = 0; j < 8; j++) a[j] += (float)v0[j] + (float)v1[j];
            }
            if (e < end) {
                int s0 = srcs[e];
                half8 v0 = *(const half8*)(gin + (size_t)s0 * D + cb);
#pragma unroll
                for (int j = 0; j < 8; j++) a[j] += (float)v0[j];
            }
        }
        const float sc = (node < N) ? dinv[node] : 0.f;
        half8 o;
#pragma unroll
        for (int j = 0; j < 8; j++) o[j] = (_Float16)(a[j] * sc);
        *(half8*)(&S[nl * LSTRIDE + cb]) = o;
    }
    __syncthreads();

    // ---- phase 2: S @ W via MFMA (A_op = W frag from LDS, B_op = S frag) ----
    f32x4 acc[8];
#pragma unroll
    for (int cc = 0; cc < 8; cc++) acc[cc] = (f32x4){0.f, 0.f, 0.f, 0.f};

    const int nl = w * 16 + l16;          // this lane's node row (B-frag)
#pragma unroll
    for (int s = 0; s < 4; s++) {
        half8 bf = *(const half8*)(&S[nl * LSTRIDE + s * 32 + q * 8]);
#pragma unroll
        for (int cc = 0; cc < 8; cc++) {
            half8 wh = *(const half8*)(&WL[(size_t)((s * 8 + cc) * 64 + lane) * 8]);
            acc[cc] = __builtin_amdgcn_mfma_f32_16x16x32_f16(wh, bf, acc[cc], 0, 0, 0);
        }
    }

    // epilogue: D[m = W-col = q*4+r][n = node = l16]
    const int node = nb0 + nl;
    if (node < N) {
        const float scale = last ? 1.0f : dinv[node];
        _Float16* rp = gout + (size_t)node * D + q * 4;
#pragma unroll
        for (int cc = 0; cc < 8; cc++) {
            const float4 bc = *(const float4*)(bias + cc * 16 + q * 4);
            half4v o;
            o[0] = (_Float16)(fmaxf(acc[cc][0] + bc.x, 0.f) * scale);
            o[1] = (_Float16)(fmaxf(acc[cc][1] + bc.y, 0.f) * scale);
            o[2] = (_Float16)(fmaxf(acc[cc][2] + bc.z, 0.f) * scale);
            o[3] = (_Float16)(fmaxf(acc[cc][3] + bc.w, 0.f) * scale);
            *(half4v*)(rp + cc * 16) = o;   // 8 B store
        }
    }
}

// ========== fused pool + MLP head: one block (256 thr) per graph ==========

__global__ __launch_bounds__(256) void k_poolhead(
        const _Float16* __restrict__ h, const int* __restrict__ batch,
        const float* __restrict__ W1, const float* __restrict__ b1,
        const float* __restrict__ W2, const float* __restrict__ b2,
        const float* __restrict__ W3, const float* __restrict__ b3,
        float* __restrict__ out, int N) {
    __shared__ int sb[2];
    __shared__ float part[4][D];
    __shared__ float v[D];
    __shared__ float z[D];
    __shared__ float red[D];

    const int g = blockIdx.x;
    const int t = threadIdx.x;

    if (t < 2) {
        int target = g + t;
        int lo = 0, hi = N;
        while (lo < hi) {
            int mid = (lo + hi) >> 1;
            if (batch[mid] < target) lo = mid + 1; else hi = mid;
        }
        sb[t] = lo;
    }
    __syncthreads();
    const int rs = sb[0], re = sb[1];

    const int w = t >> 6;
    const int lane = t & 63;
    const int c = lane * 2;

    float ax = 0.f, ay = 0.f;
    for (int r = rs + w; r < re; r += 4) {
        half2v vv = *(const half2v*)(h + (size_t)r * D + c);
        ax += (float)vv[0]; ay += (float)vv[1];
    }
    part[w][c] = ax;
    part[w][c + 1] = ay;
    __syncthreads();

    if (t < D) v[t] = part[0][t] + part[1][t] + part[2][t] + part[3][t];
    __syncthreads();

    if (t < D) {
        float s = b1[t];
        for (int k = 0; k < D; k++) s = fmaf(v[k], W1[(size_t)k * D + t], s);
        z[t] = fmaxf(s, 0.f);
    }
    __syncthreads();

    if (t < D) {
        float s = b2[t];
        for (int k = 0; k < D; k++) s = fmaf(z[k], W2[(size_t)k * D + t], s);
        red[t] = fmaxf(s, 0.f) * W3[t];
    }
    __syncthreads();
    for (int off = 64; off >= 1; off >>= 1) {
        if (t < off) red[t] += red[t + off];
        __syncthreads();
    }
    if (t == 0) out[g] = 1.f / (1.f + expf(-(red[0] + b3[0])));
}

// ================= orchestration =================

extern "C" void kernel_launch(void* const* d_in, const int* in_sizes, int n_in,
                              void* d_out, int out_size, void* d_ws, size_t ws_size,
                              hipStream_t stream) {
    const float* x     = (const float*)d_in[0];
    const int*   ei    = (const int*)d_in[1];
    const int*   batch = (const int*)d_in[2];
    const float* convW = (const float*)d_in[3];
    const float* convB = (const float*)d_in[4];
    const float* W1 = (const float*)d_in[5];
    const float* b1 = (const float*)d_in[6];
    const float* W2 = (const float*)d_in[7];
    const float* b2 = (const float*)d_in[8];
    const float* W3 = (const float*)d_in[9];
    const float* b3 = (const float*)d_in[10];
    float* out = (float*)d_out;

    const int N = in_sizes[0] / D;          // 100000
    const int E = in_sizes[1] / 2;          // 640000
    const int G = out_size;                 // 512
    const int NB = (N + 1023) / 1024;

    // ---- workspace layout ----
    char* w = (char*)d_ws;
    size_t off = 0;
    auto alloc = [&](size_t bytes) -> char* {
        char* p = w + off;
        off += (bytes + 255) & ~(size_t)255;
        return p;
    };
    float*     dinv   = (float*)alloc((size_t)N * 4);
    _Float16*  gA     = (_Float16*)alloc((size_t)N * D * 2);
    _Float16*  gB     = (_Float16*)alloc((size_t)N * D * 2);
    _Float16*  Wf     = (_Float16*)alloc((size_t)4 * D * D * 2);
    int*       counts = (int*)alloc((size_t)N * 4);
    int*       rowptr = (int*)alloc((size_t)(N + 1) * 4);
    int*       cursor = (int*)alloc((size_t)N * 4);
    int*       srcs   = (int*)alloc((size_t)E * 4);
    int*       bsums  = (int*)alloc((size_t)NB * 4);

    // ---- CSR build + weight pre-pack + input convert ----
    hipMemsetAsync(counts, 0, (size_t)N * 4, stream);
    k_count<<<(E / 4 + 255) / 256, 256, 0, stream>>>(ei, counts, E);
    k_prepw<<<32, 256, 0, stream>>>(convW, Wf);
    k_scan1<<<NB, 256, 0, stream>>>(counts, rowptr, bsums, dinv, N);
    k_cvt<<<(N * D / 8 + 255) / 256, 256, 0, stream>>>(x, dinv, gA, N * D / 8);
    k_scan2<<<1, 128, 0, stream>>>(bsums, NB);
    k_scan3<<<(N + 1 + 255) / 256, 256, 0, stream>>>(rowptr, cursor, bsums, N);
    k_fill<<<(E / 4 + 255) / 256, 256, 0, stream>>>(ei, cursor, srcs, E);

    // ---- 4 fused GCN layers (ping-pong) ----
    const int layer_grid = (N + 127) / 128;
    const _Float16* gi = gA;
    _Float16* go = gB;
    for (int l = 0; l < 4; l++) {
        k_layer<<<layer_grid, 512, 0, stream>>>(gi, rowptr, srcs, dinv,
                                                Wf + (size_t)l * D * D,
                                                convB + (size_t)l * D,
                                                go, N, l == 3);
        const _Float16* tmp = go;
        go = (_Float16*)gi;
        gi = tmp;
    }

    // ---- fused pool + head ----
    k_poolhead<<<G, 256, 0, stream>>>(gi, batch, W1, b1, W2, b2, W3, b3, out, N);
}

// Round 9
// 384.102 us; speedup vs baseline: 1.3408x; 1.1016x over previous
//
#include <hip/hip_runtime.h>
#include <math.h>

#define D 128
#define LSTRIDE 136   // LDS row stride in halves: 2-way bank alias only (free)

typedef _Float16 half8 __attribute__((ext_vector_type(8)));
typedef _Float16 half4v __attribute__((ext_vector_type(4)));
typedef _Float16 half2v __attribute__((ext_vector_type(2)));
typedef float f32x4 __attribute__((ext_vector_type(4)));

// ================= CSR build (counting sort by dst) =================

__global__ void k_count(const int* __restrict__ ei, int* __restrict__ counts, int E) {
    int e0 = (blockIdx.x * blockDim.x + threadIdx.x) * 4;
    if (e0 + 3 < E) {
        int4 d4 = *(const int4*)(ei + E + e0);
        atomicAdd(&counts[d4.x], 1);
        atomicAdd(&counts[d4.y], 1);
        atomicAdd(&counts[d4.z], 1);
        atomicAdd(&counts[d4.w], 1);
    } else {
        for (int e = e0; e < E; e++) atomicAdd(&counts[ei[E + e]], 1);
    }
}

// scan counts -> rowptr (exclusive); emits dinv = rsqrt(count+1)
__global__ __launch_bounds__(256) void k_scan1(const int* __restrict__ counts,
                                               int* __restrict__ rowptr,
                                               int* __restrict__ bsums,
                                               float* __restrict__ dinv, int N) {
    __shared__ int sh[256];
    const int t = threadIdx.x;
    const int base = blockIdx.x * 1024 + t * 4;
    int c[4];
#pragma unroll
    for (int j = 0; j < 4; j++) c[j] = (base + j < N) ? counts[base + j] : 0;
#pragma unroll
    for (int j = 0; j < 4; j++)
        if (base + j < N) dinv[base + j] = rsqrtf((float)(c[j] + 1));
    int tsum = c[0] + c[1] + c[2] + c[3];
    sh[t] = tsum;
    __syncthreads();
    for (int off = 1; off < 256; off <<= 1) {
        int v = (t >= off) ? sh[t - off] : 0;
        __syncthreads();
        sh[t] += v;
        __syncthreads();
    }
    int run = (t == 0) ? 0 : sh[t - 1];
    if (t == 255) bsums[blockIdx.x] = sh[255];
#pragma unroll
    for (int j = 0; j < 4; j++) {
        if (base + j <= N) rowptr[base + j] = run;
        run += c[j];
    }
}

__global__ __launch_bounds__(128) void k_scan2(int* __restrict__ bsums, int NB) {
    __shared__ int sh[128];
    const int t = threadIdx.x;
    sh[t] = (t < NB) ? bsums[t] : 0;
    __syncthreads();
    for (int off = 1; off < 128; off <<= 1) {
        int v = (t >= off) ? sh[t - off] : 0;
        __syncthreads();
        sh[t] += v;
        __syncthreads();
    }
    if (t < NB) bsums[t] = (t == 0) ? 0 : sh[t - 1];
}

// add block offsets; also initialize cursor = rowptr
__global__ void k_scan3(int* __restrict__ rowptr, int* __restrict__ cursor,
                        const int* __restrict__ bsums, int N) {
    int i = blockIdx.x * blockDim.x + threadIdx.x;
    if (i <= N) {
        int v = rowptr[i] + bsums[i >> 10];
        rowptr[i] = v;
        if (i < N) cursor[i] = v;
    }
}

__global__ void k_fill(const int* __restrict__ ei, int* __restrict__ cursor,
                       int* __restrict__ srcs, int E) {
    int e0 = (blockIdx.x * blockDim.x + threadIdx.x) * 4;
    if (e0 + 3 < E) {
        int4 s4 = *(const int4*)(ei + e0);
        int4 d4 = *(const int4*)(ei + E + e0);
        int p0 = atomicAdd(&cursor[d4.x], 1);
        int p1 = atomicAdd(&cursor[d4.y], 1);
        int p2 = atomicAdd(&cursor[d4.z], 1);
        int p3 = atomicAdd(&cursor[d4.w], 1);
        srcs[p0] = s4.x;
        srcs[p1] = s4.y;
        srcs[p2] = s4.z;
        srcs[p3] = s4.w;
    } else {
        for (int e = e0; e < E; e++) {
            int pos = atomicAdd(&cursor[ei[E + e]], 1);
            srcs[pos] = ei[e];
        }
    }
}

// ================= g0 = fp16(dinv[row] * x) =================

__global__ void k_cvt(const float* __restrict__ x, const float* __restrict__ dinv,
                      _Float16* __restrict__ y, int n8) {
    int i = blockIdx.x * blockDim.x + threadIdx.x;
    if (i >= n8) return;
    float s = dinv[i >> 4];
    const float4 v0 = *(const float4*)(x + (size_t)i * 8);
    const float4 v1 = *(const float4*)(x + (size_t)i * 8 + 4);
    half8 h;
    h[0] = (_Float16)(v0.x * s); h[1] = (_Float16)(v0.y * s);
    h[2] = (_Float16)(v0.z * s); h[3] = (_Float16)(v0.w * s);
    h[4] = (_Float16)(v1.x * s); h[5] = (_Float16)(v1.y * s);
    h[6] = (_Float16)(v1.z * s); h[7] = (_Float16)(v1.w * s);
    *(half8*)(y + (size_t)i * 8) = h;
}

// ======== pre-pack conv weights into MFMA fragment layout (single fp16) ========
// slot = (s*8+c)*64 + lane; element j: k = s*32 + (lane>>4)*8 + j, n = c*16 + (lane&15)

__global__ __launch_bounds__(256) void k_prepw(const float* __restrict__ convW,
                                               _Float16* __restrict__ Wf) {
    const int l = blockIdx.x >> 3;                      // layer
    const int slot = (blockIdx.x & 7) * 256 + threadIdx.x;
    const float* W = convW + (size_t)l * D * D;
    const int p = slot >> 6, ln = slot & 63;
    const int s = p >> 3, c = p & 7;
    const int kbase = s * 32 + ((ln >> 4) << 3);
    const int n = (c << 4) + (ln & 15);
    half8 hv;
#pragma unroll
    for (int j = 0; j < 8; j++) hv[j] = (_Float16)W[(size_t)(kbase + j) * D + n];
    *(half8*)(Wf + (size_t)l * D * D + (size_t)slot * 8) = hv;
}

// ============ fused layer: gout = scale ⊙ relu( (dinv ⊙ Â g) @ W + b ) ============
// Phase 1: gather — each 16-lane group owns one node, loads whole 256 B rows as
// half8 (dwordx4), unroll-4; no cross-lane reduce.
// Phase 2: S @ W via swapped-operand MFMA; W fragments read from global (L2-hot).
// Block: 512 thr = 8 waves; 128 nodes/block. LDS = S only (34.8 KB -> 4 blocks/CU).

__global__ __launch_bounds__(512) void k_layer(
        const _Float16* __restrict__ gin,
        const int* __restrict__ rowptr, const int* __restrict__ srcs,
        const float* __restrict__ dinv,
        const _Float16* __restrict__ Wf,
        const float* __restrict__ bias,
        _Float16* __restrict__ gout, int N, int last) {
    __shared__ _Float16 S[128 * LSTRIDE];   // 34.8 KB

    const int tid  = threadIdx.x;
    const int w    = tid >> 6;
    const int lane = tid & 63;
    const int q    = lane >> 4;       // group 0..3
    const int l16  = lane & 15;       // lane-in-group; col base = l16*8
    const int nb0  = blockIdx.x * 128;

    // ---- phase 1: gather; wave w covers nodes w*16..w*16+15, group q owns q*4+it ----
    const int cb = l16 * 8;
    for (int it = 0; it < 4; ++it) {
        const int nl = w * 16 + q * 4 + it;
        const int node = nb0 + nl;
        float a[8];
#pragma unroll
        for (int j = 0; j < 8; j++) a[j] = 0.f;

        if (node < N) {
            half8 sv = *(const half8*)(gin + (size_t)node * D + cb);  // self-loop
#pragma unroll
            for (int j = 0; j < 8; j++) a[j] = (float)sv[j];
            const int beg = rowptr[node];
            const int end = rowptr[node + 1];
            int e = beg;
            for (; e + 3 < end; e += 4) {
                int s0 = srcs[e], s1 = srcs[e + 1], s2 = srcs[e + 2], s3 = srcs[e + 3];
                half8 v0 = *(const half8*)(gin + (size_t)s0 * D + cb);
                half8 v1 = *(const half8*)(gin + (size_t)s1 * D + cb);
                half8 v2 = *(const half8*)(gin + (size_t)s2 * D + cb);
                half8 v3 = *(const half8*)(gin + (size_t)s3 * D + cb);
#pragma unroll
                for (int j = 0; j < 8; j++)
                    a[j] += ((float)v0[j] + (float)v1[j]) + ((float)v2[j] + (float)v3[j]);
            }
            for (; e < end; e++) {
                int s0 = srcs[e];
                half8 v0 = *(const half8*)(gin + (size_t)s0 * D + cb);
#pragma unroll
                for (int j = 0; j < 8; j++) a[j] += (float)v0[j];
            }
        }
        const float sc = (node < N) ? dinv[node] : 0.f;
        half8 o;
#pragma unroll
        for (int j = 0; j < 8; j++) o[j] = (_Float16)(a[j] * sc);
        *(half8*)(&S[nl * LSTRIDE + cb]) = o;
    }
    __syncthreads();

    // ---- phase 2: S @ W via MFMA (A_op = W frag from global/L2, B_op = S frag) ----
    f32x4 acc[8];
#pragma unroll
    for (int cc = 0; cc < 8; cc++) acc[cc] = (f32x4){0.f, 0.f, 0.f, 0.f};

    const int nl = w * 16 + l16;          // this lane's node row (B-frag)
#pragma unroll
    for (int s = 0; s < 4; s++) {
        half8 bf = *(const half8*)(&S[nl * LSTRIDE + s * 32 + q * 8]);
#pragma unroll
        for (int cc = 0; cc < 8; cc++) {
            half8 wh = *(const half8*)(Wf + (size_t)((s * 8 + cc) * 64 + lane) * 8);
            acc[cc] = __builtin_amdgcn_mfma_f32_16x16x32_f16(wh, bf, acc[cc], 0, 0, 0);
        }
    }

    // epilogue: D[m = W-col = q*4+r][n = node = l16]
    const int node = nb0 + nl;
    if (node < N) {
        const float scale = last ? 1.0f : dinv[node];
        _Float16* rp = gout + (size_t)node * D + q * 4;
#pragma unroll
        for (int cc = 0; cc < 8; cc++) {
            const float4 bc = *(const float4*)(bias + cc * 16 + q * 4);
            half4v o;
            o[0] = (_Float16)(fmaxf(acc[cc][0] + bc.x, 0.f) * scale);
            o[1] = (_Float16)(fmaxf(acc[cc][1] + bc.y, 0.f) * scale);
            o[2] = (_Float16)(fmaxf(acc[cc][2] + bc.z, 0.f) * scale);
            o[3] = (_Float16)(fmaxf(acc[cc][3] + bc.w, 0.f) * scale);
            *(half4v*)(rp + cc * 16) = o;   // 8 B store
        }
    }
}

// ========== fused pool + MLP head: one block (256 thr) per graph ==========

__global__ __launch_bounds__(256) void k_poolhead(
        const _Float16* __restrict__ h, const int* __restrict__ batch,
        const float* __restrict__ W1, const float* __restrict__ b1,
        const float* __restrict__ W2, const float* __restrict__ b2,
        const float* __restrict__ W3, const float* __restrict__ b3,
        float* __restrict__ out, int N) {
    __shared__ int sb[2];
    __shared__ float part[4][D];
    __shared__ float v[D];
    __shared__ float z[D];
    __shared__ float red[D];

    const int g = blockIdx.x;
    const int t = threadIdx.x;

    if (t < 2) {
        int target = g + t;
        int lo = 0, hi = N;
        while (lo < hi) {
            int mid = (lo + hi) >> 1;
            if (batch[mid] < target) lo = mid + 1; else hi = mid;
        }
        sb[t] = lo;
    }
    __syncthreads();
    const int rs = sb[0], re = sb[1];

    const int w = t >> 6;
    const int lane = t & 63;
    const int c = lane * 2;

    float ax = 0.f, ay = 0.f;
    for (int r = rs + w; r < re; r += 4) {
        half2v vv = *(const half2v*)(h + (size_t)r * D + c);
        ax += (float)vv[0]; ay += (float)vv[1];
    }
    part[w][c] = ax;
    part[w][c + 1] = ay;
    __syncthreads();

    if (t < D) v[t] = part[0][t] + part[1][t] + part[2][t] + part[3][t];
    __syncthreads();

    if (t < D) {
        float s = b1[t];
        for (int k = 0; k < D; k++) s = fmaf(v[k], W1[(size_t)k * D + t], s);
        z[t] = fmaxf(s, 0.f);
    }
    __syncthreads();

    if (t < D) {
        float s = b2[t];
        for (int k = 0; k < D; k++) s = fmaf(z[k], W2[(size_t)k * D + t], s);
        red[t] = fmaxf(s, 0.f) * W3[t];
    }
    __syncthreads();
    for (int off = 64; off >= 1; off >>= 1) {
        if (t < off) red[t] += red[t + off];
        __syncthreads();
    }
    if (t == 0) out[g] = 1.f / (1.f + expf(-(red[0] + b3[0])));
}

// ================= orchestration =================

extern "C" void kernel_launch(void* const* d_in, const int* in_sizes, int n_in,
                              void* d_out, int out_size, void* d_ws, size_t ws_size,
                              hipStream_t stream) {
    const float* x     = (const float*)d_in[0];
    const int*   ei    = (const int*)d_in[1];
    const int*   batch = (const int*)d_in[2];
    const float* convW = (const float*)d_in[3];
    const float* convB = (const float*)d_in[4];
    const float* W1 = (const float*)d_in[5];
    const float* b1 = (const float*)d_in[6];
    const float* W2 = (const float*)d_in[7];
    const float* b2 = (const float*)d_in[8];
    const float* W3 = (const float*)d_in[9];
    const float* b3 = (const float*)d_in[10];
    float* out = (float*)d_out;

    const int N = in_sizes[0] / D;          // 100000
    const int E = in_sizes[1] / 2;          // 640000
    const int G = out_size;                 // 512
    const int NB = (N + 1023) / 1024;

    // ---- workspace layout ----
    char* w = (char*)d_ws;
    size_t off = 0;
    auto alloc = [&](size_t bytes) -> char* {
        char* p = w + off;
        off += (bytes + 255) & ~(size_t)255;
        return p;
    };
    float*     dinv   = (float*)alloc((size_t)N * 4);
    _Float16*  gA     = (_Float16*)alloc((size_t)N * D * 2);
    _Float16*  gB     = (_Float16*)alloc((size_t)N * D * 2);
    _Float16*  Wf     = (_Float16*)alloc((size_t)4 * D * D * 2);
    int*       counts = (int*)alloc((size_t)N * 4);
    int*       rowptr = (int*)alloc((size_t)(N + 1) * 4);
    int*       cursor = (int*)alloc((size_t)N * 4);
    int*       srcs   = (int*)alloc((size_t)E * 4);
    int*       bsums  = (int*)alloc((size_t)NB * 4);

    // ---- CSR build + weight pre-pack + input convert ----
    hipMemsetAsync(counts, 0, (size_t)N * 4, stream);
    k_count<<<(E / 4 + 255) / 256, 256, 0, stream>>>(ei, counts, E);
    k_prepw<<<32, 256, 0, stream>>>(convW, Wf);
    k_scan1<<<NB, 256, 0, stream>>>(counts, rowptr, bsums, dinv, N);
    k_cvt<<<(N * D / 8 + 255) / 256, 256, 0, stream>>>(x, dinv, gA, N * D / 8);
    k_scan2<<<1, 128, 0, stream>>>(bsums, NB);
    k_scan3<<<(N + 1 + 255) / 256, 256, 0, stream>>>(rowptr, cursor, bsums, N);
    k_fill<<<(E / 4 + 255) / 256, 256, 0, stream>>>(ei, cursor, srcs, E);

    // ---- 4 fused GCN layers (ping-pong) ----
    const int layer_grid = (N + 127) / 128;
    const _Float16* gi = gA;
    _Float16* go = gB;
    for (int l = 0; l < 4; l++) {
        k_layer<<<layer_grid, 512, 0, stream>>>(gi, rowptr, srcs, dinv,
                                                Wf + (size_t)l * D * D,
                                                convB + (size_t)l * D,
                                                go, N, l == 3);
        const _Float16* tmp = go;
        go = (_Float16*)gi;
        gi = tmp;
    }

    // ---- fused pool + head ----
    k_poolhead<<<G, 256, 0, stream>>>(gi, batch, W1, b1, W2, b2, W3, b3, out, N);
}